// Round 5
// baseline (2079.436 us; speedup 1.0000x reference)
//
#include <hip/hip_runtime.h>
#include <math.h>

// GatedMDTA: B=2, C=192, H=W=256, HEADS=6, hd=32, QC=768.
// I/O dtype = fp32 (per reference source; round-2 NaN proved the bf16-I/O
// guess wrong). Internals: bf16 MFMA 16x16x32 for the three GEMM-shaped ops,
// bf16 workspace intermediates, fp32 everywhere else. m89/m91 layouts:
//   A[m=lane&15][k=quad*8+j], B[k=quad*8+j][n=lane&15], D: col=lane&15, row=quad*4+reg.
// Round 5 = round 3/4 with hipMemsetAsync replaced by a zero_init kernel
// (defensive hedge against capture-path container death; rounds 3-4 never ran
// — "MI355X container failed twice" infra error both times).

#define HEADS 6
#define CDIM 192
#define QCH 768
#define HH 256
#define WW 256
#define NPIX 65536

typedef __bf16 bf16x8 __attribute__((ext_vector_type(8)));
typedef float f32x4 __attribute__((ext_vector_type(4)));

__device__ __forceinline__ float b2f(unsigned short u) {
  union { unsigned int i; float f; } x; x.i = ((unsigned int)u) << 16; return x.f;
}
__device__ __forceinline__ unsigned short f2b(float f) {
  union { float f; unsigned int i; } x; x.f = f;
  unsigned int lsb = (x.i >> 16) & 1u;
  x.i += 0x7fffu + lsb;           // round-to-nearest-even
  return (unsigned short)(x.i >> 16);
}

// ---------------- zero-init small fp32 scratch (replaces hipMemsetAsync)
__global__ void zero_init(float* __restrict__ p, int n) {
  int i = blockIdx.x * 256 + threadIdx.x;
  if (i < n) p[i] = 0.f;
}

// ---------------- GEMM + bias: out[m][n] = sum_k A[m][k]*B[k][n] + bias[m]
// M=192 (one qkv quarter / proj), K=192, N=65536. Tile 64x64, 4 waves.
template <bool IN_F32, bool OUT_F32>
__global__ __launch_bounds__(256)
void gemm_bias(const float* __restrict__ A,      // [192][192] fp32 weights
               const void* __restrict__ Bm,      // [192][N] fp32 or bf16
               const float* __restrict__ bias,   // [192] fp32
               void* __restrict__ out)           // [192][N] fp32 or bf16
{
  const int K = 192;
  const int N = NPIX;
  int m0 = blockIdx.x * 64;
  int n0 = blockIdx.y * 64;

  __shared__ unsigned short a_lds[64][200];  // pad 192->200 (2-way alias = free)
  __shared__ unsigned short b_lds[64][200];  // n-major: b_lds[n][k]
  int t = threadIdx.x;

  // A tile: 64 rows x 192 floats, cast to bf16 into LDS
  #pragma unroll
  for (int i = 0; i < 12; ++i) {
    int idx = t + i * 256;                 // 0..3071
    int row = idx / 48, c4 = idx - row * 48;
    float4 v = *(const float4*)(A + (size_t)(m0 + row) * K + c4 * 4);
    unsigned short* dst = &a_lds[row][c4 * 4];
    dst[0] = f2b(v.x); dst[1] = f2b(v.y); dst[2] = f2b(v.z); dst[3] = f2b(v.w);
  }
  // B tile transposed on the fly (coalesced global reads over n)
  #pragma unroll
  for (int i = 0; i < 48; ++i) {
    int idx = t + i * 256;                 // 0..12287
    int n = idx & 63, k = idx >> 6;
    float v;
    if (IN_F32) v = ((const float*)Bm)[(size_t)k * N + n0 + n];
    else        v = b2f(((const unsigned short*)Bm)[(size_t)k * N + n0 + n]);
    b_lds[n][k] = f2b(v);
  }
  __syncthreads();

  int wid = t >> 6, lane = t & 63;
  int r = lane & 15, quad = lane >> 4;
  f32x4 acc[4];
  #pragma unroll
  for (int nt = 0; nt < 4; ++nt) acc[nt] = (f32x4){0.f, 0.f, 0.f, 0.f};

  #pragma unroll
  for (int kk = 0; kk < 192; kk += 32) {
    bf16x8 af = *(const bf16x8*)(&a_lds[wid * 16 + r][kk + quad * 8]);
    #pragma unroll
    for (int nt = 0; nt < 4; ++nt) {
      bf16x8 bfr = *(const bf16x8*)(&b_lds[nt * 16 + r][kk + quad * 8]);
      acc[nt] = __builtin_amdgcn_mfma_f32_16x16x32_bf16(af, bfr, acc[nt], 0, 0, 0);
    }
  }

  #pragma unroll
  for (int nt = 0; nt < 4; ++nt) {
    int col = n0 + nt * 16 + r;
    #pragma unroll
    for (int i = 0; i < 4; ++i) {
      int row = m0 + wid * 16 + quad * 4 + i;
      float v = acc[nt][i] + bias[row];
      if (OUT_F32) ((float*)out)[(size_t)row * N + col] = v;
      else ((unsigned short*)out)[(size_t)row * N + col] = f2b(v);
    }
  }
}

// ---------------- 3x3 depthwise conv + bias over one 192-channel quarter;
// optional fused per-channel sum-of-squares (for q,k). block = one (o,y) row.
__global__ __launch_bounds__(256)
void dwconv_ssq(const unsigned short* __restrict__ in,   // [192][H][W] bf16
                const float* __restrict__ w9,            // [192][9] fp32
                const float* __restrict__ bias,          // [192] fp32
                unsigned short* __restrict__ outp,       // [192][H][W] bf16
                float* __restrict__ ssq)                 // [192] or nullptr
{
  int t = threadIdx.x;
  int gid = blockIdx.x;          // o*H + y
  int y = gid & 255;
  int o = gid >> 8;              // 0..191
  const unsigned short* base = in + (size_t)o * NPIX;
  float wv[9];
  #pragma unroll
  for (int i = 0; i < 9; ++i) wv[i] = w9[o * 9 + i];
  float acc = bias[o];
  int x = t;
  #pragma unroll
  for (int dy = -1; dy <= 1; ++dy) {
    int yy = y + dy;
    if (yy < 0 || yy >= HH) continue;
    const unsigned short* rowp = base + (size_t)yy * WW;
    #pragma unroll
    for (int dx = -1; dx <= 1; ++dx) {
      int xx = x + dx;
      if (xx < 0 || xx >= WW) continue;
      acc += wv[(dy + 1) * 3 + (dx + 1)] * b2f(rowp[xx]);
    }
  }
  outp[(size_t)o * NPIX + (size_t)y * WW + x] = f2b(acc);

  if (ssq != nullptr) {          // uniform per launch -> non-divergent
    float v2 = acc * acc;
    #pragma unroll
    for (int off = 32; off; off >>= 1) v2 += __shfl_down(v2, off, 64);
    __shared__ float red[4];
    if ((t & 63) == 0) red[t >> 6] = v2;
    __syncthreads();
    if (t == 0) atomicAdd(&ssq[o], red[0] + red[1] + red[2] + red[3]);
  }
}

// ---------------- Gram: S[h][c][d] = sum_n q[h*32+c,n]*k[h*32+d,n]
__global__ __launch_bounds__(256)
void gram(const unsigned short* __restrict__ q,   // [192][N] bf16
          const unsigned short* __restrict__ k,   // [192][N] bf16
          float* __restrict__ S)                  // [HEADS][32][32]
{
  int h = blockIdx.y;
  int t = threadIdx.x, wid = t >> 6, lane = t & 63;
  int r = lane & 15, quad = lane >> 4;
  int c0 = (wid >> 1) * 16, d0 = (wid & 1) * 16;
  size_t nb = (size_t)blockIdx.x * 2048 + quad * 8;
  const unsigned short* qrow = q + (size_t)(h * 32 + c0 + r) * NPIX + nb;
  const unsigned short* krow = k + (size_t)(h * 32 + d0 + r) * NPIX + nb;
  f32x4 acc = (f32x4){0.f, 0.f, 0.f, 0.f};
  #pragma unroll 8
  for (int kk = 0; kk < 2048; kk += 32) {
    bf16x8 af  = *(const bf16x8*)(qrow + kk);
    bf16x8 bfr = *(const bf16x8*)(krow + kk);
    acc = __builtin_amdgcn_mfma_f32_16x16x32_bf16(af, bfr, acc, 0, 0, 0);
  }
  float* Sp = S + (size_t)h * 1024;
  #pragma unroll
  for (int i = 0; i < 4; ++i)
    atomicAdd(&Sp[(c0 + quad * 4 + i) * 32 + (d0 + r)], acc[i]);
}

// ---------------- scale by 1/(|q||k|)*temp, softmax over d (32-wide)
__global__ void softmax_scale(const float* __restrict__ S,      // [HEADS][1024]
                              const float* __restrict__ ssq_q,  // [192]
                              const float* __restrict__ ssq_k,  // [192]
                              const float* __restrict__ temp,   // [HEADS] fp32
                              float* __restrict__ P)            // [HEADS][1024]
{
  int h = blockIdx.x;
  int t = threadIdx.x;
  int c = t >> 5, d = t & 31;
  float nq = fmaxf(sqrtf(ssq_q[h * 32 + c]), 1e-12f);
  float nk = fmaxf(sqrtf(ssq_k[h * 32 + d]), 1e-12f);
  float v = S[(size_t)h * 1024 + t] / (nq * nk) * temp[h];
  float m = v;
  for (int off = 16; off; off >>= 1) m = fmaxf(m, __shfl_xor(m, off, 32));
  float e = expf(v - m);
  float s = e;
  for (int off = 16; off; off >>= 1) s += __shfl_xor(s, off, 32);
  P[(size_t)h * 1024 + t] = e / s;
}

// ---------------- att[c,n] = (sum_d P[c,d]*v[d,n]) * sigmoid(gate[c,n])
__global__ __launch_bounds__(256)
void pv_gate(const unsigned short* __restrict__ v,  // [192][N] bf16
             const unsigned short* __restrict__ g,  // [192][N] bf16
             const float* __restrict__ P,           // [HEADS][1024]
             unsigned short* __restrict__ att)      // [192][N] bf16
{
  int h = blockIdx.y;
  size_t n = (size_t)blockIdx.x * 256 + threadIdx.x;
  const unsigned short* vb = v + (size_t)(h * 32) * NPIX + n;
  const unsigned short* gb = g + (size_t)(h * 32) * NPIX + n;
  __shared__ float Ps[1024];
  for (int i = threadIdx.x; i < 1024; i += 256) Ps[i] = P[(size_t)h * 1024 + i];
  __syncthreads();
  float vr[32];
  #pragma unroll
  for (int d = 0; d < 32; ++d) vr[d] = b2f(vb[(size_t)d * NPIX]);
  unsigned short* outb = att + (size_t)(h * 32) * NPIX + n;
  #pragma unroll
  for (int c = 0; c < 32; ++c) {
    float a = 0.f;
    #pragma unroll
    for (int d = 0; d < 32; ++d) a += Ps[c * 32 + d] * vr[d];
    float gg = b2f(gb[(size_t)c * NPIX]);
    float sg = 1.f / (1.f + expf(-gg));
    outb[(size_t)c * NPIX] = f2b(a * sg);
  }
}

extern "C" void kernel_launch(void* const* d_in, const int* in_sizes, int n_in,
                              void* d_out, int out_size, void* d_ws, size_t ws_size,
                              hipStream_t stream)
{
  const float* x      = (const float*)d_in[0];
  const float* qkv_w  = (const float*)d_in[1];
  const float* qkv_b  = (const float*)d_in[2];
  const float* dw_w   = (const float*)d_in[3];
  const float* dw_b   = (const float*)d_in[4];
  const float* temp   = (const float*)d_in[5];
  const float* proj_w = (const float*)d_in[6];
  const float* proj_b = (const float*)d_in[7];
  float* out = (float*)d_out;

  // workspace: 3 x 25.2 MB bf16 buffers + S[2][6][1024] + ssq[2][2][192] + P[6][1024]
  char* ws = (char*)d_ws;
  const size_t qbytes = (size_t)CDIM * NPIX * 2;   // 25,165,824
  unsigned short* bufA = (unsigned short*)ws;                 // pre / att
  unsigned short* bufB = (unsigned short*)(ws + qbytes);      // post_q, later post_v
  unsigned short* bufC = (unsigned short*)(ws + 2 * qbytes);  // post_k, later post_gate
  float* S   = (float*)(ws + 3 * qbytes);      // 2*6*1024 floats
  float* ssq = S + 2 * HEADS * 1024;           // 2*2*192 floats
  float* P   = ssq + 2 * 2 * CDIM;             // 6*1024 floats (reused per batch)
  const int nz = 2 * HEADS * 1024 + 2 * 2 * CDIM;   // S + ssq
  zero_init<<<(nz + 255) / 256, 256, 0, stream>>>(S, nz);

  const dim3 ggrid(CDIM / 64, NPIX / 64);
  const int qw = CDIM * CDIM;   // quarter offset in qkv_w elements

  for (int b = 0; b < 2; ++b) {
    const float* xb = x + (size_t)b * CDIM * NPIX;
    float* outb = out + (size_t)b * CDIM * NPIX;
    float* Sb = S + (size_t)b * HEADS * 1024;
    float* sq = ssq + (size_t)b * 2 * CDIM;        // |q|^2 per channel
    float* sk = sq + CDIM;                         // |k|^2 per channel

    // q quarter (rows 0..191) -> bufB
    gemm_bias<true, false><<<ggrid, 256, 0, stream>>>(qkv_w + 0 * qw, xb, qkv_b + 0 * CDIM, bufA);
    dwconv_ssq<<<CDIM * HH, 256, 0, stream>>>(bufA, dw_w + 0 * CDIM * 9, dw_b + 0 * CDIM, bufB, sq);
    // k quarter (rows 384..575) -> bufC
    gemm_bias<true, false><<<ggrid, 256, 0, stream>>>(qkv_w + 2 * qw, xb, qkv_b + 2 * CDIM, bufA);
    dwconv_ssq<<<CDIM * HH, 256, 0, stream>>>(bufA, dw_w + 2 * CDIM * 9, dw_b + 2 * CDIM, bufC, sk);

    gram<<<dim3(32, HEADS), 256, 0, stream>>>(bufB, bufC, Sb);
    softmax_scale<<<HEADS, 1024, 0, stream>>>(Sb, sq, sk, temp, P);

    // v quarter (rows 576..767) -> bufB
    gemm_bias<true, false><<<ggrid, 256, 0, stream>>>(qkv_w + 3 * qw, xb, qkv_b + 3 * CDIM, bufA);
    dwconv_ssq<<<CDIM * HH, 256, 0, stream>>>(bufA, dw_w + 3 * CDIM * 9, dw_b + 3 * CDIM, bufB, nullptr);
    // gate quarter (rows 192..383) -> bufC
    gemm_bias<true, false><<<ggrid, 256, 0, stream>>>(qkv_w + 1 * qw, xb, qkv_b + 1 * CDIM, bufA);
    dwconv_ssq<<<CDIM * HH, 256, 0, stream>>>(bufA, dw_w + 1 * CDIM * 9, dw_b + 1 * CDIM, bufC, nullptr);

    // att -> bufA (pre_gate dead)
    pv_gate<<<dim3(NPIX / 256, HEADS), 256, 0, stream>>>(bufB, bufC, P, bufA);
    // proj -> fp32 out
    gemm_bias<false, true><<<ggrid, 256, 0, stream>>>(proj_w, bufA, proj_b, outb);
  }
}